// Round 2
// 295.696 us; speedup vs baseline: 1.0104x; 1.0104x over previous
//
#include <hip/hip_runtime.h>

typedef __attribute__((ext_vector_type(8))) short short8;
typedef __attribute__((ext_vector_type(4))) float f32x4;

#define Bsz 256
#define Cch 3
#define Him 224
#define Wim 224
#define RET 32
#define HG 1024
#define HL 256
#define GDIM 9216
#define NOUT 1280

__device__ __forceinline__ unsigned short f2bf(float x) {
  unsigned u = __float_as_uint(x);
  unsigned r = (u + 0x7fffu + ((u >> 16) & 1u)) >> 16;
  return (unsigned short)r;
}
__device__ __forceinline__ float bf2f(unsigned short h) {
  return __uint_as_float((unsigned)h << 16);
}

// async global->LDS, 16B per lane, dest = wave-uniform base + lane*16
#define GLL(gp, lp)                                                        \
  __builtin_amdgcn_global_load_lds(                                        \
      (const __attribute__((address_space(1))) unsigned int*)(gp),         \
      (__attribute__((address_space(3))) unsigned int*)(lp), 16, 0, 0)

// ---------------------------------------------------------------------------
// Foveate -> bf16 hi/lo planes g[256][9216]; 4 outputs per thread
// ---------------------------------------------------------------------------
__global__ __launch_bounds__(256) void foveate_kernel(
    const float* __restrict__ img, const float* __restrict__ loc,
    unsigned short* __restrict__ ghi, unsigned short* __restrict__ glo) {
  int q = blockIdx.x * 256 + threadIdx.x;
  int idx = q * 4;
  int b = idx / GDIM;
  int r = idx - b * GDIM;
  int z = r / (Cch * RET * RET);
  int r2 = r - z * (Cch * RET * RET);
  int c = r2 / (RET * RET);
  int p = r2 - c * (RET * RET);
  int i = p >> 5, j0 = p & 31;  // j0 is a multiple of 4
  float dr = (loc[b * 2 + 0] + 1.f) * .5f * (float)Wim;
  float dc = (loc[b * 2 + 1] + 1.f) * .5f * (float)Wim;
  int half = 16 << z;
  int top = (int)truncf(dr - (float)half), left = (int)truncf(dc - (float)half);
  const float* base = img + ((long)b * Cch + c) * (Him * Wim);
  float v[4];
  if (z == 0) {
    const float* rp = base + (top + i) * Wim + left + j0;
#pragma unroll
    for (int t = 0; t < 4; ++t) v[t] = rp[t];
  } else if (z == 1) {
    const float* rp = base + (top + 2 * i) * Wim + left + 2 * j0;
#pragma unroll
    for (int t = 0; t < 4; ++t)
      v[t] = .25f * (rp[2 * t] + rp[2 * t + 1] + rp[Wim + 2 * t] + rp[Wim + 2 * t + 1]);
  } else {
    const float* rp = base + (top + 4 * i + 1) * Wim + left + 4 * j0 + 1;
#pragma unroll
    for (int t = 0; t < 4; ++t)
      v[t] = .25f * (rp[4 * t] + rp[4 * t + 1] + rp[Wim + 4 * t] + rp[Wim + 4 * t + 1]);
  }
  unsigned short h0 = f2bf(v[0]), h1 = f2bf(v[1]), h2 = f2bf(v[2]), h3 = f2bf(v[3]);
  *(ushort4*)(ghi + idx) = make_ushort4(h0, h1, h2, h3);
  *(ushort4*)(glo + idx) =
      make_ushort4(f2bf(v[0] - bf2f(h0)), f2bf(v[1] - bf2f(h1)),
                   f2bf(v[2] - bf2f(h2)), f2bf(v[3] - bf2f(h3)));
}

// ---------------------------------------------------------------------------
// Transpose + split: in[K][N] fp32 -> outHi/outLo [N][K] bf16
// ---------------------------------------------------------------------------
__global__ __launch_bounds__(256) void tconv_kernel(
    const float* __restrict__ in, unsigned short* __restrict__ oh,
    unsigned short* __restrict__ ol, int K, int N) {
  __shared__ float tile[32][33];
  int n0 = blockIdx.x * 32, k0 = blockIdx.y * 32;
  int r = threadIdx.x >> 3, c4 = (threadIdx.x & 7) * 4;
  float4 v = *(const float4*)(in + (long)(k0 + r) * N + n0 + c4);
  tile[r][c4 + 0] = v.x; tile[r][c4 + 1] = v.y;
  tile[r][c4 + 2] = v.z; tile[r][c4 + 3] = v.w;
  __syncthreads();
  float x0 = tile[c4 + 0][r], x1 = tile[c4 + 1][r];
  float x2 = tile[c4 + 2][r], x3 = tile[c4 + 3][r];
  unsigned short h0 = f2bf(x0), h1 = f2bf(x1), h2 = f2bf(x2), h3 = f2bf(x3);
  long o = (long)(n0 + r) * K + k0 + c4;
  *(ushort4*)(oh + o) = make_ushort4(h0, h1, h2, h3);
  *(ushort4*)(ol + o) = make_ushort4(f2bf(x0 - bf2f(h0)), f2bf(x1 - bf2f(h1)),
                                     f2bf(x2 - bf2f(h2)), f2bf(x3 - bf2f(h3)));
}

// ---------------------------------------------------------------------------
// MFMA bf16x3 tile: block 128x128, 4 waves of 64x64, BK=32.
// LDS planes in fragment-linear layout [chunk][lane][8]; staging is
// global_load_lds (dest = wave-uniform base + lane*16B, which this layout
// satisfies): chunk fc, lane l holds A[m0+fc*16+(l&15)][kb+(l>>4)*8 .. +8).
// Wave w stages chunks {2w, 2w+1} of each of the 4 planes (8 loads/iter).
// ---------------------------------------------------------------------------
__device__ __forceinline__ void mfma_tile(
    const unsigned short* __restrict__ Ahi, const unsigned short* __restrict__ Alo, int lda,
    const unsigned short* __restrict__ Bhi, const unsigned short* __restrict__ Blo, int ldb,
    int m0, int n0, int kb, int iters, f32x4 acc[4][4], unsigned short* lds) {
  const int t = threadIdx.x;
  const int lane = t & 63;
  const int wid = t >> 6;
  const int wm = (t >> 7) & 1, wn = (t >> 6) & 1;
  unsigned short* pAh = lds;
  unsigned short* pAl = lds + 4096;
  unsigned short* pBh = lds + 8192;
  unsigned short* pBl = lds + 12288;
  const int c0 = 2 * wid, c1 = 2 * wid + 1;
  const int sr = lane & 15, sk = (lane >> 4) * 8;
  const long a0 = (long)(m0 + c0 * 16 + sr) * lda + kb + sk;
  const long a1 = (long)(m0 + c1 * 16 + sr) * lda + kb + sk;
  const long b0 = (long)(n0 + c0 * 16 + sr) * ldb + kb + sk;
  const long b1 = (long)(n0 + c1 * 16 + sr) * ldb + kb + sk;
  const int l0 = c0 * 512, l1 = c1 * 512;  // shorts; wave-uniform

  for (int it = 0; it < iters; ++it) {
    const long ka = (long)it * 32;
    __syncthreads();  // previous tile fully consumed
    GLL(Ahi + a0 + ka, pAh + l0);
    GLL(Ahi + a1 + ka, pAh + l1);
    GLL(Alo + a0 + ka, pAl + l0);
    GLL(Alo + a1 + ka, pAl + l1);
    GLL(Bhi + b0 + ka, pBh + l0);
    GLL(Bhi + b1 + ka, pBh + l1);
    GLL(Blo + b0 + ka, pBl + l0);
    GLL(Blo + b1 + ka, pBl + l1);
    __syncthreads();  // compiler drains vmcnt(0) before this barrier
    short8 ah[4], al[4], bh[4], bl[4];
#pragma unroll
    for (int f = 0; f < 4; ++f) {
      int ra = ((wm * 4 + f) * 64 + lane) * 8;
      int rb = ((wn * 4 + f) * 64 + lane) * 8;
      ah[f] = *(const short8*)(pAh + ra);
      al[f] = *(const short8*)(pAl + ra);
      bh[f] = *(const short8*)(pBh + rb);
      bl[f] = *(const short8*)(pBl + rb);
    }
#pragma unroll
    for (int mf = 0; mf < 4; ++mf)
#pragma unroll
      for (int nf = 0; nf < 4; ++nf) {
        acc[mf][nf] = __builtin_amdgcn_mfma_f32_16x16x32_bf16(ah[mf], bh[nf], acc[mf][nf], 0, 0, 0);
        acc[mf][nf] = __builtin_amdgcn_mfma_f32_16x16x32_bf16(ah[mf], bl[nf], acc[mf][nf], 0, 0, 0);
        acc[mf][nf] = __builtin_amdgcn_mfma_f32_16x16x32_bf16(al[mf], bh[nf], acc[mf][nf], 0, 0, 0);
      }
  }
}

__device__ __forceinline__ void epilogue(float* __restrict__ Pz, int ldp, int m0, int n0,
                                         f32x4 acc[4][4]) {
  const int t = threadIdx.x, lane = t & 63;
  const int wm = (t >> 7) & 1, wn = (t >> 6) & 1;
  const int rbase = (lane >> 4) * 4, col = lane & 15;
#pragma unroll
  for (int mf = 0; mf < 4; ++mf)
#pragma unroll
    for (int nf = 0; nf < 4; ++nf) {
      int row = m0 + wm * 64 + mf * 16 + rbase;
      int cc = n0 + wn * 64 + nf * 16 + col;
#pragma unroll
      for (int r = 0; r < 4; ++r)
        Pz[(long)(row + r) * ldp + cc] = acc[mf][nf][r];
    }
}

// gemm1: P[z][256][1024] = g @ W1 chunk, splitK=32 (chunk 288 = 9 iters of 32)
__global__ __launch_bounds__(256, 2) void gemm1_kernel(
    const unsigned short* __restrict__ ghi, const unsigned short* __restrict__ glo,
    const unsigned short* __restrict__ w1thi, const unsigned short* __restrict__ w1tlo,
    float* __restrict__ P) {
  __shared__ __align__(16) unsigned short lds[16384];
  f32x4 zz = {0.f, 0.f, 0.f, 0.f};
  f32x4 acc[4][4];
  for (int i = 0; i < 4; ++i) for (int j = 0; j < 4; ++j) acc[i][j] = zz;
  int n0 = blockIdx.x * 128, m0 = blockIdx.y * 128, z = blockIdx.z;
  mfma_tile(ghi, glo, GDIM, w1thi, w1tlo, GDIM, m0, n0, z * 288, 9, acc, lds);
  epilogue(P + (long)z * Bsz * HG, HG, m0, n0, acc);
}

// gemm2: z<8 -> h1@W3 chunk (K=128); z in {8,9} -> h2@W4 halves (K=128 each)
// -> all 200 blocks do exactly 4 K-iters (balanced)
__global__ __launch_bounds__(256, 2) void gemm2_kernel(
    const unsigned short* __restrict__ h1hi, const unsigned short* __restrict__ h1lo,
    const unsigned short* __restrict__ h2hi, const unsigned short* __restrict__ h2lo,
    const unsigned short* __restrict__ w3thi, const unsigned short* __restrict__ w3tlo,
    const unsigned short* __restrict__ w4thi, const unsigned short* __restrict__ w4tlo,
    float* __restrict__ P) {
  __shared__ __align__(16) unsigned short lds[16384];
  f32x4 zz = {0.f, 0.f, 0.f, 0.f};
  f32x4 acc[4][4];
  for (int i = 0; i < 4; ++i) for (int j = 0; j < 4; ++j) acc[i][j] = zz;
  int n0 = blockIdx.x * 128, m0 = blockIdx.y * 128, z = blockIdx.z;
  if (z < 8)
    mfma_tile(h1hi, h1lo, HG, w3thi, w3tlo, HG, m0, n0, z * 128, 4, acc, lds);
  else
    mfma_tile(h2hi, h2lo, HL, w4thi, w4tlo, HL, m0, n0, (z - 8) * 128, 4, acc, lds);
  epilogue(P + (long)z * Bsz * NOUT, NOUT, m0, n0, acc);
}

// reduce1: h1 = relu(b1 + sum_{z<32} P1[z]) -> bf16 hi/lo
__global__ __launch_bounds__(256) void reduce1_kernel(
    const float* __restrict__ P, const float* __restrict__ b1,
    unsigned short* __restrict__ h1hi, unsigned short* __restrict__ h1lo) {
  int i4 = (blockIdx.x * 256 + threadIdx.x) * 4;
  float4 s = *(const float4*)(P + i4);
  for (int z = 1; z < 32; ++z) {
    float4 p = *(const float4*)(P + (long)z * (Bsz * HG) + i4);
    s.x += p.x; s.y += p.y; s.z += p.z; s.w += p.w;
  }
  int n = i4 & (HG - 1);
  float4 bb = *(const float4*)(b1 + n);
  float v0 = fmaxf(s.x + bb.x, 0.f), v1 = fmaxf(s.y + bb.y, 0.f);
  float v2 = fmaxf(s.z + bb.z, 0.f), v3 = fmaxf(s.w + bb.w, 0.f);
  unsigned short h0 = f2bf(v0), h1 = f2bf(v1), h2 = f2bf(v2), h3 = f2bf(v3);
  *(ushort4*)(h1hi + i4) = make_ushort4(h0, h1, h2, h3);
  *(ushort4*)(h1lo + i4) = make_ushort4(f2bf(v0 - bf2f(h0)), f2bf(v1 - bf2f(h1)),
                                        f2bf(v2 - bf2f(h2)), f2bf(v3 - bf2f(h3)));
}

// h2 = relu(loc @ W2 + b2) -> bf16 hi/lo
__global__ __launch_bounds__(256) void h2_kernel(
    const float* __restrict__ loc, const float* __restrict__ W2,
    const float* __restrict__ b2, unsigned short* __restrict__ h2hi,
    unsigned short* __restrict__ h2lo) {
  int b = blockIdx.x, n = threadIdx.x;
  float s = fmaf(loc[b * 2], W2[n], fmaf(loc[b * 2 + 1], W2[HL + n], b2[n]));
  s = fmaxf(s, 0.f);
  unsigned short h = f2bf(s);
  h2hi[b * HL + n] = h;
  h2lo[b * HL + n] = f2bf(s - bf2f(h));
}

// reduce2: out = relu(relu(b3 + sum_{z<8} P2) + relu(b4 + P2[8] + P2[9]))
__global__ __launch_bounds__(256) void reduce2_kernel(
    const float* __restrict__ P, const float* __restrict__ b3,
    const float* __restrict__ b4, float* __restrict__ out) {
  int i4 = (blockIdx.x * 256 + threadIdx.x) * 4;
  float4 a = *(const float4*)(P + i4);
  for (int z = 1; z < 8; ++z) {
    float4 p = *(const float4*)(P + (long)z * (Bsz * NOUT) + i4);
    a.x += p.x; a.y += p.y; a.z += p.z; a.w += p.w;
  }
  float4 c0 = *(const float4*)(P + 8L * (Bsz * NOUT) + i4);
  float4 c1 = *(const float4*)(P + 9L * (Bsz * NOUT) + i4);
  float4 c;
  c.x = c0.x + c1.x; c.y = c0.y + c1.y; c.z = c0.z + c1.z; c.w = c0.w + c1.w;
  int n = i4 % NOUT;
  float4 b3v = *(const float4*)(b3 + n);
  float4 b4v = *(const float4*)(b4 + n);
  float4 o;
  o.x = fmaxf(fmaxf(a.x + b3v.x, 0.f) + fmaxf(c.x + b4v.x, 0.f), 0.f);
  o.y = fmaxf(fmaxf(a.y + b3v.y, 0.f) + fmaxf(c.y + b4v.y, 0.f), 0.f);
  o.z = fmaxf(fmaxf(a.z + b3v.z, 0.f) + fmaxf(c.z + b4v.z, 0.f), 0.f);
  o.w = fmaxf(fmaxf(a.w + b3v.w, 0.f) + fmaxf(c.w + b4v.w, 0.f), 0.f);
  *(float4*)(out + i4) = o;
}

extern "C" void kernel_launch(void* const* d_in, const int* in_sizes, int n_in,
                              void* d_out, int out_size, void* d_ws, size_t ws_size,
                              hipStream_t stream) {
  const float* images = (const float*)d_in[0];
  const float* locs = (const float*)d_in[1];
  const float* W1 = (const float*)d_in[2];
  const float* b1 = (const float*)d_in[3];
  const float* W2 = (const float*)d_in[4];
  const float* b2 = (const float*)d_in[5];
  const float* W3 = (const float*)d_in[6];
  const float* b3 = (const float*)d_in[7];
  const float* W4 = (const float*)d_in[8];
  const float* b4 = (const float*)d_in[9];
  float* out = (float*)d_out;

  unsigned short* ghi = (unsigned short*)d_ws;
  unsigned short* glo = ghi + (long)Bsz * GDIM;
  unsigned short* w1thi = glo + (long)Bsz * GDIM;
  unsigned short* w1tlo = w1thi + (long)GDIM * HG;
  unsigned short* w3thi = w1tlo + (long)GDIM * HG;
  unsigned short* w3tlo = w3thi + (long)HG * NOUT;
  unsigned short* w4thi = w3tlo + (long)HG * NOUT;
  unsigned short* w4tlo = w4thi + (long)HL * NOUT;
  unsigned short* h1hi = w4tlo + (long)HL * NOUT;
  unsigned short* h1lo = h1hi + (long)Bsz * HG;
  unsigned short* h2hi = h1lo + (long)Bsz * HG;
  unsigned short* h2lo = h2hi + (long)Bsz * HL;
  float* P1 = (float*)(h2lo + (long)Bsz * HL);  // 32*256*1024 fp32
  float* P2 = P1;                               // alias: P1 consumed before gemm2

  tconv_kernel<<<dim3(HG / 32, GDIM / 32), 256, 0, stream>>>(W1, w1thi, w1tlo, GDIM, HG);
  tconv_kernel<<<dim3(NOUT / 32, HG / 32), 256, 0, stream>>>(W3, w3thi, w3tlo, HG, NOUT);
  tconv_kernel<<<dim3(NOUT / 32, HL / 32), 256, 0, stream>>>(W4, w4thi, w4tlo, HL, NOUT);
  foveate_kernel<<<(Bsz * GDIM) / 1024, 256, 0, stream>>>(images, locs, ghi, glo);
  gemm1_kernel<<<dim3(HG / 128, Bsz / 128, 32), 256, 0, stream>>>(ghi, glo, w1thi, w1tlo, P1);
  reduce1_kernel<<<(Bsz * HG) / 1024, 256, 0, stream>>>(P1, b1, h1hi, h1lo);
  h2_kernel<<<Bsz, HL, 0, stream>>>(locs, W2, b2, h2hi, h2lo);
  gemm2_kernel<<<dim3(NOUT / 128, Bsz / 128, 10), 256, 0, stream>>>(
      h1hi, h1lo, h2hi, h2lo, w3thi, w3tlo, w4thi, w4tlo, P2);
  reduce2_kernel<<<(Bsz * NOUT) / 1024, 256, 0, stream>>>(P2, b3, b4, out);
}

// Round 4
// 289.074 us; speedup vs baseline: 1.0336x; 1.0229x over previous
//
#include <hip/hip_runtime.h>

typedef __attribute__((ext_vector_type(8))) short short8;
typedef __attribute__((ext_vector_type(4))) float f32x4;

#define Bsz 256
#define Cch 3
#define Him 224
#define Wim 224
#define RET 32
#define HG 1024
#define HL 256
#define GDIM 9216
#define NOUT 1280

__device__ __forceinline__ unsigned short f2bf(float x) {
  unsigned u = __float_as_uint(x);
  unsigned r = (u + 0x7fffu + ((u >> 16) & 1u)) >> 16;
  return (unsigned short)r;
}
__device__ __forceinline__ float bf2f(unsigned short h) {
  return __uint_as_float((unsigned)h << 16);
}

// async global->LDS, 16B per lane, dest = wave-uniform base + lane*16
#define GLL(gp, lp)                                                        \
  __builtin_amdgcn_global_load_lds(                                        \
      (const __attribute__((address_space(1))) unsigned int*)(gp),         \
      (__attribute__((address_space(3))) unsigned int*)(lp), 16, 0, 0)

// own-vmcnt drain + barrier as ONE asm block: compiler cannot move LDS ops
// between the wait and the barrier; each wave waits its own stages, then the
// barrier guarantees all waves' stages/reads are complete.
#define WAIT_BAR() asm volatile("s_waitcnt vmcnt(0)\n\ts_barrier" ::: "memory")

// ---------------------------------------------------------------------------
// prep: fused {foveate, tconv(W1), tconv(W3), tconv(W4)} -- one launch.
// blocks [0,2304): foveate; [2304,11520): W1; [11520,12800): W3; rest: W4.
// ---------------------------------------------------------------------------
__global__ __launch_bounds__(256) void prep_kernel(
    const float* __restrict__ img, const float* __restrict__ loc,
    unsigned short* __restrict__ ghi, unsigned short* __restrict__ glo,
    const float* __restrict__ W1, unsigned short* __restrict__ w1thi,
    unsigned short* __restrict__ w1tlo, const float* __restrict__ W3,
    unsigned short* __restrict__ w3thi, unsigned short* __restrict__ w3tlo,
    const float* __restrict__ W4, unsigned short* __restrict__ w4thi,
    unsigned short* __restrict__ w4tlo) {
  int id = blockIdx.x;
  if (id < 2304) {
    // ---- foveate: 4 outputs per thread ----
    int q = id * 256 + threadIdx.x;
    int idx = q * 4;
    int b = idx / GDIM;
    int r = idx - b * GDIM;
    int z = r / (Cch * RET * RET);
    int r2 = r - z * (Cch * RET * RET);
    int c = r2 / (RET * RET);
    int p = r2 - c * (RET * RET);
    int i = p >> 5, j0 = p & 31;  // j0 multiple of 4
    float dr = (loc[b * 2 + 0] + 1.f) * .5f * (float)Wim;
    float dc = (loc[b * 2 + 1] + 1.f) * .5f * (float)Wim;
    int half = 16 << z;
    int top = (int)truncf(dr - (float)half), left = (int)truncf(dc - (float)half);
    const float* base = img + ((long)b * Cch + c) * (Him * Wim);
    float v[4];
    if (z == 0) {
      const float* rp = base + (top + i) * Wim + left + j0;
#pragma unroll
      for (int t = 0; t < 4; ++t) v[t] = rp[t];
    } else if (z == 1) {
      const float* rp = base + (top + 2 * i) * Wim + left + 2 * j0;
#pragma unroll
      for (int t = 0; t < 4; ++t)
        v[t] = .25f * (rp[2 * t] + rp[2 * t + 1] + rp[Wim + 2 * t] + rp[Wim + 2 * t + 1]);
    } else {
      const float* rp = base + (top + 4 * i + 1) * Wim + left + 4 * j0 + 1;
#pragma unroll
      for (int t = 0; t < 4; ++t)
        v[t] = .25f * (rp[4 * t] + rp[4 * t + 1] + rp[Wim + 4 * t] + rp[Wim + 4 * t + 1]);
    }
    unsigned short h0 = f2bf(v[0]), h1 = f2bf(v[1]), h2 = f2bf(v[2]), h3 = f2bf(v[3]);
    *(ushort4*)(ghi + idx) = make_ushort4(h0, h1, h2, h3);
    *(ushort4*)(glo + idx) =
        make_ushort4(f2bf(v[0] - bf2f(h0)), f2bf(v[1] - bf2f(h1)),
                     f2bf(v[2] - bf2f(h2)), f2bf(v[3] - bf2f(h3)));
    return;
  }
  // ---- transpose+split: in[K][N] fp32 -> oh/ol [N][K] bf16 ----
  id -= 2304;
  const float* in;
  unsigned short *oh, *ol;
  int K, N, bx, by;
  if (id < 9216) {
    in = W1; oh = w1thi; ol = w1tlo; K = GDIM; N = HG;
    bx = id & 31; by = id >> 5;
  } else if (id < 10496) {
    id -= 9216;
    in = W3; oh = w3thi; ol = w3tlo; K = HG; N = NOUT;
    bx = id % 40; by = id / 40;
  } else {
    id -= 10496;
    in = W4; oh = w4thi; ol = w4tlo; K = HL; N = NOUT;
    bx = id % 40; by = id / 40;
  }
  __shared__ float tile[32][33];
  int n0 = bx * 32, k0 = by * 32;
  int r = threadIdx.x >> 3, c4 = (threadIdx.x & 7) * 4;
  float4 v = *(const float4*)(in + (long)(k0 + r) * N + n0 + c4);
  tile[r][c4 + 0] = v.x; tile[r][c4 + 1] = v.y;
  tile[r][c4 + 2] = v.z; tile[r][c4 + 3] = v.w;
  __syncthreads();
  float x0 = tile[c4 + 0][r], x1 = tile[c4 + 1][r];
  float x2 = tile[c4 + 2][r], x3 = tile[c4 + 3][r];
  unsigned short h0 = f2bf(x0), h1 = f2bf(x1), h2 = f2bf(x2), h3 = f2bf(x3);
  long o = (long)(n0 + r) * K + k0 + c4;
  *(ushort4*)(oh + o) = make_ushort4(h0, h1, h2, h3);
  *(ushort4*)(ol + o) = make_ushort4(f2bf(x0 - bf2f(h0)), f2bf(x1 - bf2f(h1)),
                                     f2bf(x2 - bf2f(h2)), f2bf(x3 - bf2f(h3)));
}

// ---------------------------------------------------------------------------
// MFMA bf16x3 tile: block 128x128, 4 waves of 64x64, BK=32.
// TRUE 2-PHASE: double-buffered LDS (2 x 32 KB), STAGE(next) issued BEFORE
// compute(cur); one own-vmcnt+barrier per iter (no full drain before compute).
// Fragment-linear layout [chunk][lane][8]; global_load_lds 16B staging.
// ---------------------------------------------------------------------------
__device__ __forceinline__ void mfma_tile(
    const unsigned short* __restrict__ Ahi, const unsigned short* __restrict__ Alo, int lda,
    const unsigned short* __restrict__ Bhi, const unsigned short* __restrict__ Blo, int ldb,
    int m0, int n0, int kb, int iters, f32x4 acc[4][4], unsigned short* lds) {
  const int t = threadIdx.x;
  const int lane = t & 63;
  const int wid = t >> 6;
  const int wm = (t >> 7) & 1, wn = (t >> 6) & 1;
  const int c0 = 2 * wid, c1 = 2 * wid + 1;
  const int sr = lane & 15, sk = (lane >> 4) * 8;
  const long a0 = (long)(m0 + c0 * 16 + sr) * lda + kb + sk;
  const long a1 = (long)(m0 + c1 * 16 + sr) * lda + kb + sk;
  const long b0 = (long)(n0 + c0 * 16 + sr) * ldb + kb + sk;
  const long b1 = (long)(n0 + c1 * 16 + sr) * ldb + kb + sk;
  const int l0 = c0 * 512, l1 = c1 * 512;  // shorts; wave-uniform

#define STAGE(buf, tt)                                                     \
  do {                                                                     \
    unsigned short* L_ = lds + (buf) * 16384;                              \
    const long ka_ = (long)(tt) * 32;                                      \
    GLL(Ahi + a0 + ka_, L_ + l0);                                          \
    GLL(Ahi + a1 + ka_, L_ + l1);                                          \
    GLL(Alo + a0 + ka_, L_ + 4096 + l0);                                   \
    GLL(Alo + a1 + ka_, L_ + 4096 + l1);                                   \
    GLL(Bhi + b0 + ka_, L_ + 8192 + l0);                                   \
    GLL(Bhi + b1 + ka_, L_ + 8192 + l1);                                   \
    GLL(Blo + b0 + ka_, L_ + 12288 + l0);                                  \
    GLL(Blo + b1 + ka_, L_ + 12288 + l1);                                  \
  } while (0)

  STAGE(0, 0);
  WAIT_BAR();
  int cur = 0;
  for (int it = 0; it < iters; ++it) {
    if (it + 1 < iters) STAGE(cur ^ 1, it + 1);  // prefetch overlaps compute
    unsigned short* L = lds + cur * 16384;
    short8 ah[4], al[4], bh[4], bl[4];
#pragma unroll
    for (int f = 0; f < 4; ++f) {
      int ra = ((wm * 4 + f) * 64 + lane) * 8;
      int rb = ((wn * 4 + f) * 64 + lane) * 8;
      ah[f] = *(const short8*)(L + ra);
      al[f] = *(const short8*)(L + 4096 + ra);
      bh[f] = *(const short8*)(L + 8192 + rb);
      bl[f] = *(const short8*)(L + 12288 + rb);
    }
#pragma unroll
    for (int mf = 0; mf < 4; ++mf)
#pragma unroll
      for (int nf = 0; nf < 4; ++nf) {
        acc[mf][nf] = __builtin_amdgcn_mfma_f32_16x16x32_bf16(ah[mf], bh[nf], acc[mf][nf], 0, 0, 0);
        acc[mf][nf] = __builtin_amdgcn_mfma_f32_16x16x32_bf16(ah[mf], bl[nf], acc[mf][nf], 0, 0, 0);
        acc[mf][nf] = __builtin_amdgcn_mfma_f32_16x16x32_bf16(al[mf], bh[nf], acc[mf][nf], 0, 0, 0);
      }
    WAIT_BAR();  // own next-tile stages done; all waves' reads of cur done
    cur ^= 1;
  }
#undef STAGE
}

__device__ __forceinline__ void epilogue(float* __restrict__ Pz, int ldp, int m0, int n0,
                                         f32x4 acc[4][4]) {
  const int t = threadIdx.x, lane = t & 63;
  const int wm = (t >> 7) & 1, wn = (t >> 6) & 1;
  const int rbase = (lane >> 4) * 4, col = lane & 15;
#pragma unroll
  for (int mf = 0; mf < 4; ++mf)
#pragma unroll
    for (int nf = 0; nf < 4; ++nf) {
      int row = m0 + wm * 64 + mf * 16 + rbase;
      int cc = n0 + wn * 64 + nf * 16 + col;
#pragma unroll
      for (int r = 0; r < 4; ++r)
        Pz[(long)(row + r) * ldp + cc] = acc[mf][nf][r];
    }
}

// gemm1: P[z][256][1024] = g @ W1 chunk, splitK=32 (chunk 288 = 9 iters of 32)
__global__ __launch_bounds__(256, 2) void gemm1_kernel(
    const unsigned short* __restrict__ ghi, const unsigned short* __restrict__ glo,
    const unsigned short* __restrict__ w1thi, const unsigned short* __restrict__ w1tlo,
    float* __restrict__ P) {
  __shared__ __align__(16) unsigned short lds[32768];  // 2 x 32 KB
  f32x4 zz = {0.f, 0.f, 0.f, 0.f};
  f32x4 acc[4][4];
  for (int i = 0; i < 4; ++i) for (int j = 0; j < 4; ++j) acc[i][j] = zz;
  int n0 = blockIdx.x * 128, m0 = blockIdx.y * 128, z = blockIdx.z;
  mfma_tile(ghi, glo, GDIM, w1thi, w1tlo, GDIM, m0, n0, z * 288, 9, acc, lds);
  epilogue(P + (long)z * Bsz * HG, HG, m0, n0, acc);
}

// gemm2: z<8 -> h1@W3 chunk (K=128); z in {8,9} -> h2@W4 halves (K=128 each)
__global__ __launch_bounds__(256, 2) void gemm2_kernel(
    const unsigned short* __restrict__ h1hi, const unsigned short* __restrict__ h1lo,
    const unsigned short* __restrict__ h2hi, const unsigned short* __restrict__ h2lo,
    const unsigned short* __restrict__ w3thi, const unsigned short* __restrict__ w3tlo,
    const unsigned short* __restrict__ w4thi, const unsigned short* __restrict__ w4tlo,
    float* __restrict__ P) {
  __shared__ __align__(16) unsigned short lds[32768];
  f32x4 zz = {0.f, 0.f, 0.f, 0.f};
  f32x4 acc[4][4];
  for (int i = 0; i < 4; ++i) for (int j = 0; j < 4; ++j) acc[i][j] = zz;
  int n0 = blockIdx.x * 128, m0 = blockIdx.y * 128, z = blockIdx.z;
  if (z < 8)
    mfma_tile(h1hi, h1lo, HG, w3thi, w3tlo, HG, m0, n0, z * 128, 4, acc, lds);
  else
    mfma_tile(h2hi, h2lo, HL, w4thi, w4tlo, HL, m0, n0, (z - 8) * 128, 4, acc, lds);
  epilogue(P + (long)z * Bsz * NOUT, NOUT, m0, n0, acc);
}

// reduce1 + h2 fused: blocks [0,256): h1 = relu(b1 + sum_z P1[z]);
// blocks [256,512): h2 = relu(loc @ W2 + b2)
__global__ __launch_bounds__(256) void reduce1h2_kernel(
    const float* __restrict__ P, const float* __restrict__ b1,
    unsigned short* __restrict__ h1hi, unsigned short* __restrict__ h1lo,
    const float* __restrict__ loc, const float* __restrict__ W2,
    const float* __restrict__ b2, unsigned short* __restrict__ h2hi,
    unsigned short* __restrict__ h2lo) {
  if (blockIdx.x < 256) {
    int i4 = (blockIdx.x * 256 + threadIdx.x) * 4;
    float4 s = *(const float4*)(P + i4);
    for (int z = 1; z < 32; ++z) {
      float4 p = *(const float4*)(P + (long)z * (Bsz * HG) + i4);
      s.x += p.x; s.y += p.y; s.z += p.z; s.w += p.w;
    }
    int n = i4 & (HG - 1);
    float4 bb = *(const float4*)(b1 + n);
    float v0 = fmaxf(s.x + bb.x, 0.f), v1 = fmaxf(s.y + bb.y, 0.f);
    float v2 = fmaxf(s.z + bb.z, 0.f), v3 = fmaxf(s.w + bb.w, 0.f);
    unsigned short h0 = f2bf(v0), h1 = f2bf(v1), h2 = f2bf(v2), h3 = f2bf(v3);
    *(ushort4*)(h1hi + i4) = make_ushort4(h0, h1, h2, h3);
    *(ushort4*)(h1lo + i4) = make_ushort4(f2bf(v0 - bf2f(h0)), f2bf(v1 - bf2f(h1)),
                                          f2bf(v2 - bf2f(h2)), f2bf(v3 - bf2f(h3)));
  } else {
    int b = blockIdx.x - 256, n = threadIdx.x;
    float s = fmaf(loc[b * 2], W2[n], fmaf(loc[b * 2 + 1], W2[HL + n], b2[n]));
    s = fmaxf(s, 0.f);
    unsigned short h = f2bf(s);
    h2hi[b * HL + n] = h;
    h2lo[b * HL + n] = f2bf(s - bf2f(h));
  }
}

// reduce2: out = relu(relu(b3 + sum_{z<8} P2) + relu(b4 + P2[8] + P2[9]))
__global__ __launch_bounds__(256) void reduce2_kernel(
    const float* __restrict__ P, const float* __restrict__ b3,
    const float* __restrict__ b4, float* __restrict__ out) {
  int i4 = (blockIdx.x * 256 + threadIdx.x) * 4;
  float4 a = *(const float4*)(P + i4);
  for (int z = 1; z < 8; ++z) {
    float4 p = *(const float4*)(P + (long)z * (Bsz * NOUT) + i4);
    a.x += p.x; a.y += p.y; a.z += p.z; a.w += p.w;
  }
  float4 c0 = *(const float4*)(P + 8L * (Bsz * NOUT) + i4);
  float4 c1 = *(const float4*)(P + 9L * (Bsz * NOUT) + i4);
  float4 c;
  c.x = c0.x + c1.x; c.y = c0.y + c1.y; c.z = c0.z + c1.z; c.w = c0.w + c1.w;
  int n = i4 % NOUT;
  float4 b3v = *(const float4*)(b3 + n);
  float4 b4v = *(const float4*)(b4 + n);
  float4 o;
  o.x = fmaxf(fmaxf(a.x + b3v.x, 0.f) + fmaxf(c.x + b4v.x, 0.f), 0.f);
  o.y = fmaxf(fmaxf(a.y + b3v.y, 0.f) + fmaxf(c.y + b4v.y, 0.f), 0.f);
  o.z = fmaxf(fmaxf(a.z + b3v.z, 0.f) + fmaxf(c.z + b4v.z, 0.f), 0.f);
  o.w = fmaxf(fmaxf(a.w + b3v.w, 0.f) + fmaxf(c.w + b4v.w, 0.f), 0.f);
  *(float4*)(out + i4) = o;
}

extern "C" void kernel_launch(void* const* d_in, const int* in_sizes, int n_in,
                              void* d_out, int out_size, void* d_ws, size_t ws_size,
                              hipStream_t stream) {
  const float* images = (const float*)d_in[0];
  const float* locs = (const float*)d_in[1];
  const float* W1 = (const float*)d_in[2];
  const float* b1 = (const float*)d_in[3];
  const float* W2 = (const float*)d_in[4];
  const float* b2 = (const float*)d_in[5];
  const float* W3 = (const float*)d_in[6];
  const float* b3 = (const float*)d_in[7];
  const float* W4 = (const float*)d_in[8];
  const float* b4 = (const float*)d_in[9];
  float* out = (float*)d_out;

  unsigned short* ghi = (unsigned short*)d_ws;
  unsigned short* glo = ghi + (long)Bsz * GDIM;
  unsigned short* w1thi = glo + (long)Bsz * GDIM;
  unsigned short* w1tlo = w1thi + (long)GDIM * HG;
  unsigned short* w3thi = w1tlo + (long)GDIM * HG;
  unsigned short* w3tlo = w3thi + (long)HG * NOUT;
  unsigned short* w4thi = w3tlo + (long)HG * NOUT;
  unsigned short* w4tlo = w4thi + (long)HL * NOUT;
  unsigned short* h1hi = w4tlo + (long)HL * NOUT;
  unsigned short* h1lo = h1hi + (long)Bsz * HG;
  unsigned short* h2hi = h1lo + (long)Bsz * HG;
  unsigned short* h2lo = h2hi + (long)Bsz * HL;
  float* P1 = (float*)(h2lo + (long)Bsz * HL);  // 32*256*1024 fp32
  float* P2 = P1;                               // alias: P1 consumed before gemm2

  prep_kernel<<<13120, 256, 0, stream>>>(images, locs, ghi, glo, W1, w1thi, w1tlo,
                                         W3, w3thi, w3tlo, W4, w4thi, w4tlo);
  gemm1_kernel<<<dim3(HG / 128, Bsz / 128, 32), 256, 0, stream>>>(ghi, glo, w1thi, w1tlo, P1);
  reduce1h2_kernel<<<512, 256, 0, stream>>>(P1, b1, h1hi, h1lo, locs, W2, b2, h2hi, h2lo);
  gemm2_kernel<<<dim3(NOUT / 128, Bsz / 128, 10), 256, 0, stream>>>(
      h1hi, h1lo, h2hi, h2lo, w3thi, w3tlo, w4thi, w4tlo, P2);
  reduce2_kernel<<<(Bsz * NOUT) / 1024, 256, 0, stream>>>(P2, b3, b4, out);
}